// Round 24
// baseline (198.049 us; speedup 1.0000x reference)
//
#include <hip/hip_runtime.h>
#include <hip/hip_fp16.h>

// fixed-point scale for weighted-degree accumulation (2^25)
#define FIX 33554432.0f
#define FIXINV (1.0f / 33554432.0f)

typedef unsigned long long ull;
typedef unsigned uint4e __attribute__((ext_vector_type(4)));  // nontemporal-compatible

#define EB 4096     // edges per block in part1 (16/thread)
#define CSH 9       // bucket = 512 dst nodes
#define CNODES 512
#define MAXNB 256   // static LDS histogram capacity (NB=196 here)
#define CAPC 1280   // records per (bucket,class) cell; mean 1020, 8-sigma slack
#define CAPB (CAPC * 8)  // csr records per bucket region

// ---------------- half15 pack/unpack (ew >= 0 -> sign bit 0, fits 15 bits) ----------------
__device__ __forceinline__ unsigned f2h15(float f) {
    union { __half h; unsigned short u; } cv;
    cv.h = __float2half(f);
    return (unsigned)cv.u;
}
__device__ __forceinline__ float h15f(unsigned p) {
    union { unsigned short u; __half h; } cv;
    cv.u = (unsigned short)(p >> 17);
    return __half2float(cv.h);
}

// ---------------- init per-cell cursors to cell bases ----------------
__global__ void initcur_k(int* gcur, int M) {
    int i = blockIdx.x * blockDim.x + threadIdx.x;
    if (i < M) gcur[i * 16] = i * CAPC;
}

// ---------------- phase 1: LDS-staged bucket partition, per-(bucket,class) cells ----------------
// rec = ewbits[57:26] | src[25:9] | (dst&511)[8:0]
// 16 edges/thread; stage 1 claims local slots (ls only), stage 3 re-reads (L1-hot) and stores.
__global__ void part1_k(const int* __restrict__ src, const int* __restrict__ dst,
                        const float* __restrict__ ew, int* gcur, ull* __restrict__ tmp,
                        int e, int NB) {
    __shared__ int lh[MAXNB];
    __shared__ int lb[MAXNB];
    for (int i = threadIdx.x; i < NB; i += blockDim.x) lh[i] = 0;
    __syncthreads();
    int cls = blockIdx.x & 7;
    int base = blockIdx.x * EB + threadIdx.x * 16;
    bool full = (blockIdx.x + 1) * EB <= e;  // block-uniform
    int ls[16];
    if (full) {
#pragma unroll
        for (int c = 0; c < 4; ++c) {
            int4 d4 = *reinterpret_cast<const int4*>(dst + base + c * 4);
            ls[c * 4 + 0] = atomicAdd(&lh[d4.x >> CSH], 1);
            ls[c * 4 + 1] = atomicAdd(&lh[d4.y >> CSH], 1);
            ls[c * 4 + 2] = atomicAdd(&lh[d4.z >> CSH], 1);
            ls[c * 4 + 3] = atomicAdd(&lh[d4.w >> CSH], 1);
        }
    } else {
        for (int j = 0; j < 16; ++j) {
            int i = base + j;
            ls[j] = (i < e) ? atomicAdd(&lh[dst[i] >> CSH], 1) : 0;
        }
    }
    __syncthreads();
    for (int i = threadIdx.x; i < NB; i += blockDim.x) {
        int c = lh[i];
        lb[i] = c ? atomicAdd(&gcur[(i * 8 + cls) * 16], c) : 0;
    }
    __syncthreads();
    if (full) {
#pragma unroll
        for (int c = 0; c < 4; ++c) {
            int4 s4 = *reinterpret_cast<const int4*>(src + base + c * 4);
            int4 d4 = *reinterpret_cast<const int4*>(dst + base + c * 4);
            float4 e4 = *reinterpret_cast<const float4*>(ew + base + c * 4);
            int s[4] = {s4.x, s4.y, s4.z, s4.w};
            int d[4] = {d4.x, d4.y, d4.z, d4.w};
            float ev[4] = {e4.x, e4.y, e4.z, e4.w};
#pragma unroll
            for (int j = 0; j < 4; ++j) {
                int bk = d[j] >> CSH;
                ull rec = ((ull)__float_as_uint(ev[j]) << 26) | ((ull)(unsigned)s[j] << 9) |
                          (ull)(unsigned)(d[j] & (CNODES - 1));
                int idx = lb[bk] + ls[c * 4 + j];
                int lim = (bk * 8 + cls + 1) * CAPC;  // cell capacity guard
                if (idx < lim) tmp[idx] = rec;
            }
        }
    } else {
        for (int j = 0; j < 16; ++j) {
            int i = base + j;
            if (i < e) {
                int s = src[i], d = dst[i];
                float ev = ew[i];
                int bk = d >> CSH;
                ull rec = ((ull)__float_as_uint(ev) << 26) | ((ull)(unsigned)s << 9) |
                          (ull)(unsigned)(d & (CNODES - 1));
                int idx = lb[bk] + ls[j];
                int lim = (bk * 8 + cls + 1) * CAPC;
                if (idx < lim) tmp[idx] = rec;
            }
        }
    }
}

// ---------------- phase 2: per-bucket deg/dinv + rowbe + compressed node-sorted CSR ----------------
__global__ __launch_bounds__(CNODES) void part2_k(const ull* __restrict__ tmp,
                                                  const int* __restrict__ gcur,
                                                  float* __restrict__ dinv,
                                                  uint2* __restrict__ rowbe,
                                                  unsigned* __restrict__ csr, int n) {
    __shared__ ull ldc[CNODES];   // hi32: cnt, lo32: fixed-point deg
    __shared__ int sc[CNODES];    // scan buffer, then cursor
    int b = blockIdx.x;
    int tid = threadIdx.x;
    ldc[tid] = 0;
    __syncthreads();
    // pass A: count + weighted degree over the bucket's 8 cells
    for (int x = 0; x < 8; ++x) {
        int cell = b * 8 + x;
        int cbase = cell * CAPC;
        int ccnt = gcur[cell * 16] - cbase;
        if (ccnt > CAPC) ccnt = CAPC;
        for (int i = tid; i < ccnt; i += CNODES) {
            ull rec = tmp[(long)cbase + i];
            int dlo = (int)(rec & (CNODES - 1));
            float ewv = __uint_as_float((unsigned)(rec >> 26));
            atomicAdd(&ldc[dlo], (1ULL << 32) | (ull)__float2uint_rn(ewv * FIX));
        }
    }
    __syncthreads();
    ull v = ldc[tid];
    int cnt = (int)(v >> 32);
    int node = b * CNODES + tid;
    if (node < n) {
        float d = (float)(unsigned)((unsigned)(v & 0xffffffffu) + (1u << 25)) * FIXINV;
        dinv[node] = rsqrtf(d);  // d >= 1 always
    }
    // inclusive scan of cnt (Hillis-Steele)
    sc[tid] = cnt;
    __syncthreads();
    for (int off = 1; off < CNODES; off <<= 1) {
        int x = (tid >= off) ? sc[tid - off] : 0;
        __syncthreads();
        sc[tid] += x;
        __syncthreads();
    }
    int rbeg = b * CAPB + sc[tid] - cnt;  // csr slot base in this bucket's region
    if (node < n) rowbe[node] = make_uint2((unsigned)rbeg, (unsigned)(rbeg + cnt));
    __syncthreads();
    sc[tid] = rbeg;  // reuse as cursor
    __syncthreads();
    // pass B: scatter compressed records (tmp L2-resident from pass A)
    for (int x = 0; x < 8; ++x) {
        int cell = b * 8 + x;
        int cbase = cell * CAPC;
        int ccnt = gcur[cell * 16] - cbase;
        if (ccnt > CAPC) ccnt = CAPC;
        for (int i = tid; i < ccnt; i += CNODES) {
            ull rec = tmp[(long)cbase + i];
            int dlo = (int)(rec & (CNODES - 1));
            unsigned s = (unsigned)((rec >> 9) & 0x1FFFF);
            float ewv = __uint_as_float((unsigned)(rec >> 26));
            int slot = atomicAdd(&sc[dlo], 1);
            csr[slot] = (f2h15(ewv) << 17) | s;
        }
    }
}

// ---------------- x -> fp16 rows at stride 40 (80B rows, 16B-aligned), dinv-folded ----------------
__global__ void tohalf_k(const float* __restrict__ x, const float* __restrict__ dinv,
                         __half* __restrict__ out, int n) {
    long gid = (long)blockIdx.x * blockDim.x + threadIdx.x;
    if (gid >= (long)n * 5) return;
    int row = (int)(gid / 5), c = (int)(gid % 5);
    float di = dinv[row];
    const float4* src = reinterpret_cast<const float4*>(x + (long)row * 40 + c * 8);
    float4 a = src[0], bb = src[1];
    __half2* dst = reinterpret_cast<__half2*>(out + (long)row * 40 + c * 8);
    dst[0] = __floats2half2_rn(di * a.x, di * a.y);
    dst[1] = __floats2half2_rn(di * a.z, di * a.w);
    dst[2] = __floats2half2_rn(di * bb.x, di * bb.y);
    dst[3] = __floats2half2_rn(di * bb.z, di * bb.w);
}

// ---------------- edge-gather core: 4B records, nt loads, 16-deep main batch ----------------
__device__ __forceinline__ float gather_core(const unsigned* __restrict__ csr,
                                             const __half* __restrict__ f16,
                                             int beg, int end, int ln) {
    float acc = 0.0f;
    int t = beg;
    while (t < end && (t & 3)) {  // peel to 16B alignment
        unsigned p = csr[t];
        acc = fmaf(h15f(p), __half2float(f16[(long)(p & 0x1FFFF) * 40 + ln]), acc);
        ++t;
    }
    for (; t + 15 < end; t += 16) {
        uint4e a = __builtin_nontemporal_load(reinterpret_cast<const uint4e*>(csr + t));
        uint4e b = __builtin_nontemporal_load(reinterpret_cast<const uint4e*>(csr + t + 4));
        uint4e c = __builtin_nontemporal_load(reinterpret_cast<const uint4e*>(csr + t + 8));
        uint4e d = __builtin_nontemporal_load(reinterpret_cast<const uint4e*>(csr + t + 12));
        float v0 = __half2float(f16[(long)(a.x & 0x1FFFF) * 40 + ln]);
        float v1 = __half2float(f16[(long)(a.y & 0x1FFFF) * 40 + ln]);
        float v2 = __half2float(f16[(long)(a.z & 0x1FFFF) * 40 + ln]);
        float v3 = __half2float(f16[(long)(a.w & 0x1FFFF) * 40 + ln]);
        float v4 = __half2float(f16[(long)(b.x & 0x1FFFF) * 40 + ln]);
        float v5 = __half2float(f16[(long)(b.y & 0x1FFFF) * 40 + ln]);
        float v6 = __half2float(f16[(long)(b.z & 0x1FFFF) * 40 + ln]);
        float v7 = __half2float(f16[(long)(b.w & 0x1FFFF) * 40 + ln]);
        float v8 = __half2float(f16[(long)(c.x & 0x1FFFF) * 40 + ln]);
        float v9 = __half2float(f16[(long)(c.y & 0x1FFFF) * 40 + ln]);
        float va = __half2float(f16[(long)(c.z & 0x1FFFF) * 40 + ln]);
        float vb = __half2float(f16[(long)(c.w & 0x1FFFF) * 40 + ln]);
        float vc = __half2float(f16[(long)(d.x & 0x1FFFF) * 40 + ln]);
        float vd = __half2float(f16[(long)(d.y & 0x1FFFF) * 40 + ln]);
        float ve = __half2float(f16[(long)(d.z & 0x1FFFF) * 40 + ln]);
        float vf = __half2float(f16[(long)(d.w & 0x1FFFF) * 40 + ln]);
        acc = fmaf(h15f(a.x), v0, acc);
        acc = fmaf(h15f(a.y), v1, acc);
        acc = fmaf(h15f(a.z), v2, acc);
        acc = fmaf(h15f(a.w), v3, acc);
        acc = fmaf(h15f(b.x), v4, acc);
        acc = fmaf(h15f(b.y), v5, acc);
        acc = fmaf(h15f(b.z), v6, acc);
        acc = fmaf(h15f(b.w), v7, acc);
        acc = fmaf(h15f(c.x), v8, acc);
        acc = fmaf(h15f(c.y), v9, acc);
        acc = fmaf(h15f(c.z), va, acc);
        acc = fmaf(h15f(c.w), vb, acc);
        acc = fmaf(h15f(d.x), vc, acc);
        acc = fmaf(h15f(d.y), vd, acc);
        acc = fmaf(h15f(d.z), ve, acc);
        acc = fmaf(h15f(d.w), vf, acc);
    }
    for (; t + 7 < end; t += 8) {
        uint4e a = __builtin_nontemporal_load(reinterpret_cast<const uint4e*>(csr + t));
        uint4e b = __builtin_nontemporal_load(reinterpret_cast<const uint4e*>(csr + t + 4));
        float v0 = __half2float(f16[(long)(a.x & 0x1FFFF) * 40 + ln]);
        float v1 = __half2float(f16[(long)(a.y & 0x1FFFF) * 40 + ln]);
        float v2 = __half2float(f16[(long)(a.z & 0x1FFFF) * 40 + ln]);
        float v3 = __half2float(f16[(long)(a.w & 0x1FFFF) * 40 + ln]);
        float v4 = __half2float(f16[(long)(b.x & 0x1FFFF) * 40 + ln]);
        float v5 = __half2float(f16[(long)(b.y & 0x1FFFF) * 40 + ln]);
        float v6 = __half2float(f16[(long)(b.z & 0x1FFFF) * 40 + ln]);
        float v7 = __half2float(f16[(long)(b.w & 0x1FFFF) * 40 + ln]);
        acc = fmaf(h15f(a.x), v0, acc);
        acc = fmaf(h15f(a.y), v1, acc);
        acc = fmaf(h15f(a.z), v2, acc);
        acc = fmaf(h15f(a.w), v3, acc);
        acc = fmaf(h15f(b.x), v4, acc);
        acc = fmaf(h15f(b.y), v5, acc);
        acc = fmaf(h15f(b.z), v6, acc);
        acc = fmaf(h15f(b.w), v7, acc);
    }
    for (; t + 3 < end; t += 4) {
        uint4e a = __builtin_nontemporal_load(reinterpret_cast<const uint4e*>(csr + t));
        float v0 = __half2float(f16[(long)(a.x & 0x1FFFF) * 40 + ln]);
        float v1 = __half2float(f16[(long)(a.y & 0x1FFFF) * 40 + ln]);
        float v2 = __half2float(f16[(long)(a.z & 0x1FFFF) * 40 + ln]);
        float v3 = __half2float(f16[(long)(a.w & 0x1FFFF) * 40 + ln]);
        acc = fmaf(h15f(a.x), v0, acc);
        acc = fmaf(h15f(a.y), v1, acc);
        acc = fmaf(h15f(a.z), v2, acc);
        acc = fmaf(h15f(a.w), v3, acc);
    }
    for (; t < end; ++t) {
        unsigned p = csr[t];
        acc = fmaf(h15f(p), __half2float(f16[(long)(p & 0x1FFFF) * 40 + ln]), acc);
    }
    return acc;
}

// ---------------- FUSED layer 1: gather (C=40) + linear1 (40 -> 64) + ReLU, fp16 h ----------------
__global__ __launch_bounds__(256) void gatherlin_k(const uint2* __restrict__ rowbe,
                                                   const unsigned* __restrict__ csr,
                                                   const __half* __restrict__ feat16,
                                                   const float* __restrict__ dinv,
                                                   const float* __restrict__ W1,
                                                   const float* __restrict__ b1,
                                                   __half* __restrict__ h16, int n) {
    int lane = threadIdx.x & 63;
    int wid = blockIdx.x * (blockDim.x >> 6) + (threadIdx.x >> 6);
    int nwaves = gridDim.x * (blockDim.x >> 6);
    float w1reg[40];
#pragma unroll
    for (int k = 0; k < 40; ++k) w1reg[k] = W1[k * 64 + lane];  // C=64: all lanes valid
    float b1v = b1[lane];
    int ln = (lane < 40) ? lane : 0;  // clamp: lanes 40-63 re-read lane0's bytes (same lines)
    for (int node = wid; node < n; node += nwaves) {
        uint2 be = rowbe[node];
        int beg = __builtin_amdgcn_readfirstlane((int)be.x);
        int end = __builtin_amdgcn_readfirstlane((int)be.y);
        float accE = gather_core(csr, feat16, beg, end, ln);
        float selfv = __half2float(feat16[(long)node * 40 + ln]);
        float di = dinv[node];
        unsigned aggu = __float_as_uint(di * (accE + selfv));
        float a0 = 0.0f, a1 = 0.0f, a2 = 0.0f, a3 = 0.0f;
#pragma unroll
        for (int k = 0; k < 40; k += 4) {
            a0 = fmaf(__uint_as_float(__builtin_amdgcn_readlane(aggu, k + 0)), w1reg[k + 0], a0);
            a1 = fmaf(__uint_as_float(__builtin_amdgcn_readlane(aggu, k + 1)), w1reg[k + 1], a1);
            a2 = fmaf(__uint_as_float(__builtin_amdgcn_readlane(aggu, k + 2)), w1reg[k + 2], a2);
            a3 = fmaf(__uint_as_float(__builtin_amdgcn_readlane(aggu, k + 3)), w1reg[k + 3], a3);
        }
        float hv = fmaxf((a0 + a1) + (a2 + a3) + b1v, 0.0f);
        union { __half h; unsigned short u; } cv;
        cv.h = __float2half(hv);
        __builtin_nontemporal_store(cv.u, reinterpret_cast<unsigned short*>(&h16[(long)node * 64 + lane]));
    }
}

// ---------------- linear 2: xl2_16 = half(dinv * (h @ W2)), fp16 in/out ----------------
__global__ __launch_bounds__(256) void linear2_k(const __half* __restrict__ h16,
                                                 const float* __restrict__ W2,
                                                 __half* __restrict__ y16,
                                                 const float* __restrict__ dinv, int n) {
    int lane = threadIdx.x & 63;
    int wid = blockIdx.x * (blockDim.x >> 6) + (threadIdx.x >> 6);
    int nwaves = gridDim.x * (blockDim.x >> 6);
    float wreg[64];
#pragma unroll
    for (int k = 0; k < 64; ++k) wreg[k] = (lane < 40) ? W2[k * 40 + lane] : 0.0f;
    for (int node = wid; node < n; node += nwaves) {
        float xv = __half2float(h16[(long)node * 64 + lane]);  // K=64: all lanes load
        unsigned xu = __float_as_uint(xv);
        float a0 = 0.0f, a1 = 0.0f, a2 = 0.0f, a3 = 0.0f;
#pragma unroll
        for (int k = 0; k < 64; k += 4) {
            a0 = fmaf(__uint_as_float(__builtin_amdgcn_readlane(xu, k + 0)), wreg[k + 0], a0);
            a1 = fmaf(__uint_as_float(__builtin_amdgcn_readlane(xu, k + 1)), wreg[k + 1], a1);
            a2 = fmaf(__uint_as_float(__builtin_amdgcn_readlane(xu, k + 2)), wreg[k + 2], a2);
            a3 = fmaf(__uint_as_float(__builtin_amdgcn_readlane(xu, k + 3)), wreg[k + 3], a3);
        }
        float acc = (a0 + a1) + (a2 + a3);
        if (lane < 40) y16[(long)node * 40 + lane] = __float2half(dinv[node] * acc);
    }
}

// ---------------- final gather at C=40: out = dinv*(accE + self) + b ----------------
__global__ void gather40_k(const uint2* __restrict__ rowbe, const unsigned* __restrict__ csr,
                           const __half* __restrict__ feat16, const float* __restrict__ dinv,
                           const float* __restrict__ b, float* __restrict__ out, int n) {
    int node = (int)(((long)blockIdx.x * blockDim.x + threadIdx.x) >> 6);
    int lane = threadIdx.x & 63;
    if (node >= n) return;
    uint2 be = rowbe[node];
    int beg = __builtin_amdgcn_readfirstlane((int)be.x);
    int end = __builtin_amdgcn_readfirstlane((int)be.y);
    if (lane >= 40) return;
    float accE = gather_core(csr, feat16, beg, end, lane);
    float selfv = __half2float(feat16[(long)node * 40 + lane]);
    float di = dinv[node];
    out[(long)node * 40 + lane] = di * (accE + selfv) + b[lane];
}

extern "C" void kernel_launch(void* const* d_in, const int* in_sizes, int n_in,
                              void* d_out, int out_size, void* d_ws, size_t ws_size,
                              hipStream_t stream) {
    const float* x = (const float*)d_in[0];
    const int* ei = (const int*)d_in[1];
    const float* ew = (const float*)d_in[2];
    const float* W1 = (const float*)d_in[3];
    const float* b1 = (const float*)d_in[4];
    const float* W2 = (const float*)d_in[5];
    const float* b2 = (const float*)d_in[6];
    float* out = (float*)d_out;

    const int n = in_sizes[0] / 40;   // 100000
    const int e = in_sizes[2];        // 1600000
    const int* srcp = ei;
    const int* dstp = ei + e;
    const int NB = (n + CNODES - 1) >> CSH;  // 196 buckets
    const int M = NB * 8;                    // (bucket, class) cells

    // ws layout (4B units):
    // csr[NB*CAPB] | tmp[NB*8*CAPC ull] | dinv[n] | rowbe[2n] | gcur[M*16] |
    // h16 (64n halves = 32n words) | xl2_16 (40n halves)
    // sh16 (40n halves = 20n words) overlays tmp (dead after part2)
    unsigned* csr = (unsigned*)d_ws;
    ull* tmp = (ull*)(csr + (long)NB * CAPB);
    float* dinv = (float*)(tmp + (long)NB * 8 * CAPC);
    uint2* rowbe = (uint2*)(dinv + n);
    int* gcur = (int*)(rowbe + n);
    __half* h16 = (__half*)(gcur + M * 16);
    __half* xl2_16 = h16 + (long)n * 64;
    __half* sh16 = (__half*)tmp;          // overlay: tmp dead after part2

    const int B = 256;
    auto cdiv = [](long a, long b) { return (int)((a + b - 1) / b); };
    const int egrid = cdiv(e, EB);

    // ---- CSR build (shared by both layers) ----
    initcur_k<<<cdiv(M, B), B, 0, stream>>>(gcur, M);
    part1_k<<<egrid, B, 0, stream>>>(srcp, dstp, ew, gcur, tmp, e, NB);
    part2_k<<<NB, CNODES, 0, stream>>>(tmp, gcur, dinv, rowbe, csr, n);

    // ---- x -> fp16 (dinv-folded, stride-40 rows) ----
    tohalf_k<<<cdiv((long)n * 5, B), B, 0, stream>>>(x, dinv, sh16, n);

    // ---- layer 1 fused: h16 = half(relu((A@x)@W1+b1)) ----
    gatherlin_k<<<4096, B, 0, stream>>>(rowbe, csr, sh16, dinv, W1, b1, h16, n);

    // ---- layer 2: xl2_16 = half(dinv * (h @ W2)); out = A_norm-gather + b2 ----
    linear2_k<<<8192, B, 0, stream>>>(h16, W2, xl2_16, dinv, n);
    gather40_k<<<cdiv((long)n * 64, B), B, 0, stream>>>(rowbe, csr, xl2_16, dinv, b2, out, n);
}

// Round 25
// 184.242 us; speedup vs baseline: 1.0749x; 1.0749x over previous
//
#include <hip/hip_runtime.h>
#include <hip/hip_fp16.h>

// fixed-point scale for weighted-degree accumulation (2^25)
#define FIX 33554432.0f
#define FIXINV (1.0f / 33554432.0f)

typedef unsigned long long ull;
typedef unsigned uint4e __attribute__((ext_vector_type(4)));  // nontemporal-compatible

#define EB 4096     // edges per block in part1 (16/thread)
#define CSH 9       // bucket = 512 dst nodes
#define CNODES 512
#define MAXNB 256   // static LDS histogram capacity (NB=196 here)
#define CAPC 1280   // records per (bucket,class) cell; mean 1020, 8-sigma slack
#define CAPB (CAPC * 8)  // csr records per bucket region

// ---------------- half15 pack/unpack (ew >= 0 -> sign bit 0, fits 15 bits) ----------------
__device__ __forceinline__ unsigned f2h15(float f) {
    union { __half h; unsigned short u; } cv;
    cv.h = __float2half(f);
    return (unsigned)cv.u;
}
__device__ __forceinline__ float h15f(unsigned p) {
    union { unsigned short u; __half h; } cv;
    cv.u = (unsigned short)(p >> 17);
    return __half2float(cv.h);
}

// ---------------- init per-cell cursors to cell bases ----------------
__global__ void initcur_k(int* gcur, int M) {
    int i = blockIdx.x * blockDim.x + threadIdx.x;
    if (i < M) gcur[i * 16] = i * CAPC;
}

// ---------------- phase 1: LDS-staged bucket partition, per-(bucket,class) cells ----------------
// rec = ewbits[57:26] | src[25:9] | (dst&511)[8:0]
// 16 edges/thread; stage 1 claims local slots (ls only), stage 3 re-reads (L1-hot) and stores.
__global__ void part1_k(const int* __restrict__ src, const int* __restrict__ dst,
                        const float* __restrict__ ew, int* gcur, ull* __restrict__ tmp,
                        int e, int NB) {
    __shared__ int lh[MAXNB];
    __shared__ int lb[MAXNB];
    for (int i = threadIdx.x; i < NB; i += blockDim.x) lh[i] = 0;
    __syncthreads();
    int cls = blockIdx.x & 7;
    int base = blockIdx.x * EB + threadIdx.x * 16;
    bool full = (blockIdx.x + 1) * EB <= e;  // block-uniform
    int ls[16];
    if (full) {
#pragma unroll
        for (int c = 0; c < 4; ++c) {
            int4 d4 = *reinterpret_cast<const int4*>(dst + base + c * 4);
            ls[c * 4 + 0] = atomicAdd(&lh[d4.x >> CSH], 1);
            ls[c * 4 + 1] = atomicAdd(&lh[d4.y >> CSH], 1);
            ls[c * 4 + 2] = atomicAdd(&lh[d4.z >> CSH], 1);
            ls[c * 4 + 3] = atomicAdd(&lh[d4.w >> CSH], 1);
        }
    } else {
        for (int j = 0; j < 16; ++j) {
            int i = base + j;
            ls[j] = (i < e) ? atomicAdd(&lh[dst[i] >> CSH], 1) : 0;
        }
    }
    __syncthreads();
    for (int i = threadIdx.x; i < NB; i += blockDim.x) {
        int c = lh[i];
        lb[i] = c ? atomicAdd(&gcur[(i * 8 + cls) * 16], c) : 0;
    }
    __syncthreads();
    if (full) {
#pragma unroll
        for (int c = 0; c < 4; ++c) {
            int4 s4 = *reinterpret_cast<const int4*>(src + base + c * 4);
            int4 d4 = *reinterpret_cast<const int4*>(dst + base + c * 4);
            float4 e4 = *reinterpret_cast<const float4*>(ew + base + c * 4);
            int s[4] = {s4.x, s4.y, s4.z, s4.w};
            int d[4] = {d4.x, d4.y, d4.z, d4.w};
            float ev[4] = {e4.x, e4.y, e4.z, e4.w};
#pragma unroll
            for (int j = 0; j < 4; ++j) {
                int bk = d[j] >> CSH;
                ull rec = ((ull)__float_as_uint(ev[j]) << 26) | ((ull)(unsigned)s[j] << 9) |
                          (ull)(unsigned)(d[j] & (CNODES - 1));
                int idx = lb[bk] + ls[c * 4 + j];
                int lim = (bk * 8 + cls + 1) * CAPC;  // cell capacity guard
                if (idx < lim) tmp[idx] = rec;
            }
        }
    } else {
        for (int j = 0; j < 16; ++j) {
            int i = base + j;
            if (i < e) {
                int s = src[i], d = dst[i];
                float ev = ew[i];
                int bk = d >> CSH;
                ull rec = ((ull)__float_as_uint(ev) << 26) | ((ull)(unsigned)s << 9) |
                          (ull)(unsigned)(d & (CNODES - 1));
                int idx = lb[bk] + ls[j];
                int lim = (bk * 8 + cls + 1) * CAPC;
                if (idx < lim) tmp[idx] = rec;
            }
        }
    }
}

// ---------------- phase 2: per-bucket deg/dinv + rowbe + compressed node-sorted CSR ----------------
__global__ __launch_bounds__(CNODES) void part2_k(const ull* __restrict__ tmp,
                                                  const int* __restrict__ gcur,
                                                  float* __restrict__ dinv,
                                                  uint2* __restrict__ rowbe,
                                                  unsigned* __restrict__ csr, int n) {
    __shared__ ull ldc[CNODES];   // hi32: cnt, lo32: fixed-point deg
    __shared__ int sc[CNODES];    // scan buffer, then cursor
    int b = blockIdx.x;
    int tid = threadIdx.x;
    ldc[tid] = 0;
    __syncthreads();
    // pass A: count + weighted degree over the bucket's 8 cells
    for (int x = 0; x < 8; ++x) {
        int cell = b * 8 + x;
        int cbase = cell * CAPC;
        int ccnt = gcur[cell * 16] - cbase;
        if (ccnt > CAPC) ccnt = CAPC;
        for (int i = tid; i < ccnt; i += CNODES) {
            ull rec = tmp[(long)cbase + i];
            int dlo = (int)(rec & (CNODES - 1));
            float ewv = __uint_as_float((unsigned)(rec >> 26));
            atomicAdd(&ldc[dlo], (1ULL << 32) | (ull)__float2uint_rn(ewv * FIX));
        }
    }
    __syncthreads();
    ull v = ldc[tid];
    int cnt = (int)(v >> 32);
    int node = b * CNODES + tid;
    if (node < n) {
        float d = (float)(unsigned)((unsigned)(v & 0xffffffffu) + (1u << 25)) * FIXINV;
        dinv[node] = rsqrtf(d);  // d >= 1 always
    }
    // inclusive scan of cnt (Hillis-Steele)
    sc[tid] = cnt;
    __syncthreads();
    for (int off = 1; off < CNODES; off <<= 1) {
        int x = (tid >= off) ? sc[tid - off] : 0;
        __syncthreads();
        sc[tid] += x;
        __syncthreads();
    }
    int rbeg = b * CAPB + sc[tid] - cnt;  // csr slot base in this bucket's region
    if (node < n) rowbe[node] = make_uint2((unsigned)rbeg, (unsigned)(rbeg + cnt));
    __syncthreads();
    sc[tid] = rbeg;  // reuse as cursor
    __syncthreads();
    // pass B: scatter compressed records (tmp L2-resident from pass A)
    for (int x = 0; x < 8; ++x) {
        int cell = b * 8 + x;
        int cbase = cell * CAPC;
        int ccnt = gcur[cell * 16] - cbase;
        if (ccnt > CAPC) ccnt = CAPC;
        for (int i = tid; i < ccnt; i += CNODES) {
            ull rec = tmp[(long)cbase + i];
            int dlo = (int)(rec & (CNODES - 1));
            unsigned s = (unsigned)((rec >> 9) & 0x1FFFF);
            float ewv = __uint_as_float((unsigned)(rec >> 26));
            int slot = atomicAdd(&sc[dlo], 1);
            csr[slot] = (f2h15(ewv) << 17) | s;
        }
    }
}

// ---------------- x -> fp16 rows at stride 40 (80B rows, 16B-aligned), dinv-folded ----------------
__global__ void tohalf_k(const float* __restrict__ x, const float* __restrict__ dinv,
                         __half* __restrict__ out, int n) {
    long gid = (long)blockIdx.x * blockDim.x + threadIdx.x;
    if (gid >= (long)n * 5) return;
    int row = (int)(gid / 5), c = (int)(gid % 5);
    float di = dinv[row];
    const float4* src = reinterpret_cast<const float4*>(x + (long)row * 40 + c * 8);
    float4 a = src[0], bb = src[1];
    __half2* dst = reinterpret_cast<__half2*>(out + (long)row * 40 + c * 8);
    dst[0] = __floats2half2_rn(di * a.x, di * a.y);
    dst[1] = __floats2half2_rn(di * a.z, di * a.w);
    dst[2] = __floats2half2_rn(di * bb.x, di * bb.y);
    dst[3] = __floats2half2_rn(di * bb.z, di * bb.w);
}

// ---------------- edge-gather core: 4B records, non-temporal ext-vector loads, 8-deep ----------------
__device__ __forceinline__ float gather_core(const unsigned* __restrict__ csr,
                                             const __half* __restrict__ f16,
                                             int beg, int end, int ln) {
    float acc = 0.0f;
    int t = beg;
    while (t < end && (t & 3)) {  // peel to 16B alignment
        unsigned p = csr[t];
        acc = fmaf(h15f(p), __half2float(f16[(long)(p & 0x1FFFF) * 40 + ln]), acc);
        ++t;
    }
    for (; t + 7 < end; t += 8) {
        uint4e a = __builtin_nontemporal_load(reinterpret_cast<const uint4e*>(csr + t));
        uint4e b = __builtin_nontemporal_load(reinterpret_cast<const uint4e*>(csr + t + 4));
        float v0 = __half2float(f16[(long)(a.x & 0x1FFFF) * 40 + ln]);
        float v1 = __half2float(f16[(long)(a.y & 0x1FFFF) * 40 + ln]);
        float v2 = __half2float(f16[(long)(a.z & 0x1FFFF) * 40 + ln]);
        float v3 = __half2float(f16[(long)(a.w & 0x1FFFF) * 40 + ln]);
        float v4 = __half2float(f16[(long)(b.x & 0x1FFFF) * 40 + ln]);
        float v5 = __half2float(f16[(long)(b.y & 0x1FFFF) * 40 + ln]);
        float v6 = __half2float(f16[(long)(b.z & 0x1FFFF) * 40 + ln]);
        float v7 = __half2float(f16[(long)(b.w & 0x1FFFF) * 40 + ln]);
        acc = fmaf(h15f(a.x), v0, acc);
        acc = fmaf(h15f(a.y), v1, acc);
        acc = fmaf(h15f(a.z), v2, acc);
        acc = fmaf(h15f(a.w), v3, acc);
        acc = fmaf(h15f(b.x), v4, acc);
        acc = fmaf(h15f(b.y), v5, acc);
        acc = fmaf(h15f(b.z), v6, acc);
        acc = fmaf(h15f(b.w), v7, acc);
    }
    for (; t + 3 < end; t += 4) {
        uint4e a = __builtin_nontemporal_load(reinterpret_cast<const uint4e*>(csr + t));
        float v0 = __half2float(f16[(long)(a.x & 0x1FFFF) * 40 + ln]);
        float v1 = __half2float(f16[(long)(a.y & 0x1FFFF) * 40 + ln]);
        float v2 = __half2float(f16[(long)(a.z & 0x1FFFF) * 40 + ln]);
        float v3 = __half2float(f16[(long)(a.w & 0x1FFFF) * 40 + ln]);
        acc = fmaf(h15f(a.x), v0, acc);
        acc = fmaf(h15f(a.y), v1, acc);
        acc = fmaf(h15f(a.z), v2, acc);
        acc = fmaf(h15f(a.w), v3, acc);
    }
    for (; t < end; ++t) {
        unsigned p = csr[t];
        acc = fmaf(h15f(p), __half2float(f16[(long)(p & 0x1FFFF) * 40 + ln]), acc);
    }
    return acc;
}

// ---------------- FUSED layer 1: gather (C=40) + linear1 (40 -> 64) + ReLU, fp16 h ----------------
__global__ __launch_bounds__(256) void gatherlin_k(const uint2* __restrict__ rowbe,
                                                   const unsigned* __restrict__ csr,
                                                   const __half* __restrict__ feat16,
                                                   const float* __restrict__ dinv,
                                                   const float* __restrict__ W1,
                                                   const float* __restrict__ b1,
                                                   __half* __restrict__ h16, int n) {
    int lane = threadIdx.x & 63;
    int wid = blockIdx.x * (blockDim.x >> 6) + (threadIdx.x >> 6);
    int nwaves = gridDim.x * (blockDim.x >> 6);
    float w1reg[40];
#pragma unroll
    for (int k = 0; k < 40; ++k) w1reg[k] = W1[k * 64 + lane];  // C=64: all lanes valid
    float b1v = b1[lane];
    int ln = (lane < 40) ? lane : 0;  // clamp: lanes 40-63 re-read lane0's bytes (same lines)
    for (int node = wid; node < n; node += nwaves) {
        uint2 be = rowbe[node];
        int beg = __builtin_amdgcn_readfirstlane((int)be.x);
        int end = __builtin_amdgcn_readfirstlane((int)be.y);
        float accE = gather_core(csr, feat16, beg, end, ln);
        float selfv = __half2float(feat16[(long)node * 40 + ln]);
        float di = dinv[node];
        unsigned aggu = __float_as_uint(di * (accE + selfv));
        float a0 = 0.0f, a1 = 0.0f, a2 = 0.0f, a3 = 0.0f;
#pragma unroll
        for (int k = 0; k < 40; k += 4) {
            a0 = fmaf(__uint_as_float(__builtin_amdgcn_readlane(aggu, k + 0)), w1reg[k + 0], a0);
            a1 = fmaf(__uint_as_float(__builtin_amdgcn_readlane(aggu, k + 1)), w1reg[k + 1], a1);
            a2 = fmaf(__uint_as_float(__builtin_amdgcn_readlane(aggu, k + 2)), w1reg[k + 2], a2);
            a3 = fmaf(__uint_as_float(__builtin_amdgcn_readlane(aggu, k + 3)), w1reg[k + 3], a3);
        }
        float hv = fmaxf((a0 + a1) + (a2 + a3) + b1v, 0.0f);
        union { __half h; unsigned short u; } cv;
        cv.h = __float2half(hv);
        __builtin_nontemporal_store(cv.u, reinterpret_cast<unsigned short*>(&h16[(long)node * 64 + lane]));
    }
}

// ---------------- linear 2: xl2_16 = half(dinv * (h @ W2)), fp16 in/out ----------------
__global__ __launch_bounds__(256) void linear2_k(const __half* __restrict__ h16,
                                                 const float* __restrict__ W2,
                                                 __half* __restrict__ y16,
                                                 const float* __restrict__ dinv, int n) {
    int lane = threadIdx.x & 63;
    int wid = blockIdx.x * (blockDim.x >> 6) + (threadIdx.x >> 6);
    int nwaves = gridDim.x * (blockDim.x >> 6);
    float wreg[64];
#pragma unroll
    for (int k = 0; k < 64; ++k) wreg[k] = (lane < 40) ? W2[k * 40 + lane] : 0.0f;
    for (int node = wid; node < n; node += nwaves) {
        float xv = __half2float(h16[(long)node * 64 + lane]);  // K=64: all lanes load
        unsigned xu = __float_as_uint(xv);
        float a0 = 0.0f, a1 = 0.0f, a2 = 0.0f, a3 = 0.0f;
#pragma unroll
        for (int k = 0; k < 64; k += 4) {
            a0 = fmaf(__uint_as_float(__builtin_amdgcn_readlane(xu, k + 0)), wreg[k + 0], a0);
            a1 = fmaf(__uint_as_float(__builtin_amdgcn_readlane(xu, k + 1)), wreg[k + 1], a1);
            a2 = fmaf(__uint_as_float(__builtin_amdgcn_readlane(xu, k + 2)), wreg[k + 2], a2);
            a3 = fmaf(__uint_as_float(__builtin_amdgcn_readlane(xu, k + 3)), wreg[k + 3], a3);
        }
        float acc = (a0 + a1) + (a2 + a3);
        if (lane < 40) y16[(long)node * 40 + lane] = __float2half(dinv[node] * acc);
    }
}

// ---------------- final gather at C=40: out = dinv*(accE + self) + b ----------------
__global__ void gather40_k(const uint2* __restrict__ rowbe, const unsigned* __restrict__ csr,
                           const __half* __restrict__ feat16, const float* __restrict__ dinv,
                           const float* __restrict__ b, float* __restrict__ out, int n) {
    int node = (int)(((long)blockIdx.x * blockDim.x + threadIdx.x) >> 6);
    int lane = threadIdx.x & 63;
    if (node >= n) return;
    uint2 be = rowbe[node];
    int beg = __builtin_amdgcn_readfirstlane((int)be.x);
    int end = __builtin_amdgcn_readfirstlane((int)be.y);
    if (lane >= 40) return;
    float accE = gather_core(csr, feat16, beg, end, lane);
    float selfv = __half2float(feat16[(long)node * 40 + lane]);
    float di = dinv[node];
    out[(long)node * 40 + lane] = di * (accE + selfv) + b[lane];
}

extern "C" void kernel_launch(void* const* d_in, const int* in_sizes, int n_in,
                              void* d_out, int out_size, void* d_ws, size_t ws_size,
                              hipStream_t stream) {
    const float* x = (const float*)d_in[0];
    const int* ei = (const int*)d_in[1];
    const float* ew = (const float*)d_in[2];
    const float* W1 = (const float*)d_in[3];
    const float* b1 = (const float*)d_in[4];
    const float* W2 = (const float*)d_in[5];
    const float* b2 = (const float*)d_in[6];
    float* out = (float*)d_out;

    const int n = in_sizes[0] / 40;   // 100000
    const int e = in_sizes[2];        // 1600000
    const int* srcp = ei;
    const int* dstp = ei + e;
    const int NB = (n + CNODES - 1) >> CSH;  // 196 buckets
    const int M = NB * 8;                    // (bucket, class) cells

    // ws layout (4B units):
    // csr[NB*CAPB] | tmp[NB*8*CAPC ull] | dinv[n] | rowbe[2n] | gcur[M*16] |
    // h16 (64n halves = 32n words) | xl2_16 (40n halves)
    // sh16 (40n halves = 20n words) overlays tmp (dead after part2)
    unsigned* csr = (unsigned*)d_ws;
    ull* tmp = (ull*)(csr + (long)NB * CAPB);
    float* dinv = (float*)(tmp + (long)NB * 8 * CAPC);
    uint2* rowbe = (uint2*)(dinv + n);
    int* gcur = (int*)(rowbe + n);
    __half* h16 = (__half*)(gcur + M * 16);
    __half* xl2_16 = h16 + (long)n * 64;
    __half* sh16 = (__half*)tmp;          // overlay: tmp dead after part2

    const int B = 256;
    auto cdiv = [](long a, long b) { return (int)((a + b - 1) / b); };
    const int egrid = cdiv(e, EB);

    // ---- CSR build (shared by both layers) ----
    initcur_k<<<cdiv(M, B), B, 0, stream>>>(gcur, M);
    part1_k<<<egrid, B, 0, stream>>>(srcp, dstp, ew, gcur, tmp, e, NB);
    part2_k<<<NB, CNODES, 0, stream>>>(tmp, gcur, dinv, rowbe, csr, n);

    // ---- x -> fp16 (dinv-folded, stride-40 rows) ----
    tohalf_k<<<cdiv((long)n * 5, B), B, 0, stream>>>(x, dinv, sh16, n);

    // ---- layer 1 fused: h16 = half(relu((A@x)@W1+b1)) ----
    gatherlin_k<<<4096, B, 0, stream>>>(rowbe, csr, sh16, dinv, W1, b1, h16, n);

    // ---- layer 2: xl2_16 = half(dinv * (h @ W2)); out = A_norm-gather + b2 ----
    linear2_k<<<4096, B, 0, stream>>>(h16, W2, xl2_16, dinv, n);
    gather40_k<<<cdiv((long)n * 64, B), B, 0, stream>>>(rowbe, csr, xl2_16, dinv, b2, out, n);
}